// Round 11
// baseline (491.062 us; speedup 1.0000x reference)
//
#include <hip/hip_runtime.h>
#include <math.h>

#define TPB 256
#define TPBS 1024
#define EPSBN 1e-5f
#define PW 16

typedef __attribute__((ext_vector_type(8))) short bf8v;   // 8 x bf16 (4 VGPR)
typedef __attribute__((ext_vector_type(4))) float f4v;    // MFMA acc

static __device__ __forceinline__ unsigned short f2bf(float f) {
    union { float f; unsigned u; } v; v.f = f;
    unsigned r = v.u + 0x7fffu + ((v.u >> 16) & 1u);
    return (unsigned short)(r >> 16);
}
static __device__ __forceinline__ float bf2f(unsigned short h) {
    union { unsigned u; float f; } v; v.u = ((unsigned)h) << 16;
    return v.f;
}

// ---- workspace layout (float element offsets); total 26,865,664 floats (~107.5 MB) ----
#define WS_WAG      0u
#define WS_FWP      9216u
#define WS_SC1      209920u
#define WS_SH1      209952u
#define WS_SCK      209984u
#define WS_SHK      213120u
#define WS_G        216256u
#define WS_C        232897u
#define WS_WNEW     234187u
#define WS_BN1PART  235520u
#define WS_BN2PART  497664u
#define WS_PHI      1021952u
#define WS_FPART    1550336u
#define WS_GPART    5220352u
#define WS_CPART    7399936u
#define WS_PMAX     7598080u
#define WS_PMINH    20443136u
#define WS_TOTAL    26865664ull

// kW: pack conv2 weights into A-frag order (bf16) and fc1 weights into B-frag order (bf16)
__global__ __launch_bounds__(TPB) void kW_pack(const float* __restrict__ w2,
                                               const float* __restrict__ fw,
                                               unsigned* __restrict__ wAg_u,
                                               unsigned* __restrict__ fwp_u) {
    int e = blockIdx.x * TPB + threadIdx.x;
    if (e < 9216) {
        int jj = e & 3, lane = (e >> 2) & 63, mt = (e >> 8) & 3, t = e >> 10;
        int j0 = jj * 2;
        int co = mt * 16 + (lane & 15);
        int ci = (lane >> 4) * 8 + j0;
        unsigned h0 = f2bf(w2[(co * 32 + ci) * 9 + t]);
        unsigned h1 = f2bf(w2[(co * 32 + ci + 1) * 9 + t]);
        wAg_u[e] = h0 | (h1 << 16);
    } else if (e < 9216 + 200704) {
        int f = e - 9216;
        int kk = (f & 15) * 2, n = (f >> 4) & 127, g = f >> 11;
        unsigned h0 = f2bf(fw[n * 3136 + g * 32 + kk]);
        unsigned h1 = f2bf(fw[n * 3136 + g * 32 + kk + 1]);
        fwp_u[f] = h0 | (h1 << 16);
    }
}

// k1: BN1 stats via channel-independent patch moments S[9], Q[45].
__global__ __launch_bounds__(TPB) void k1_conv1_stats(const float* __restrict__ x,
                                                      float* __restrict__ qpart) {
    __shared__ float xs[900];
    __shared__ float red[4][54];
    int tid = threadIdx.x;
    float acc[54];
#pragma unroll
    for (int i = 0; i < 54; ++i) acc[i] = 0.f;
    for (int img = 0; img < 16; ++img) {
        int n = blockIdx.x * 16 + img;
        for (int i = tid; i < 900; i += TPB) xs[i] = 0.f;
        __syncthreads();
        for (int i = tid; i < 784; i += TPB) {
            int r = i / 28, c = i % 28;
            xs[(r + 1) * 30 + (c + 1)] = x[n * 784 + i];
        }
        __syncthreads();
        for (int p = tid; p < 784; p += TPB) {
            int oy = p / 28, ox = p % 28;
            float v[9];
#pragma unroll
            for (int t = 0; t < 9; ++t) v[t] = xs[(oy + t / 3) * 30 + ox + (t % 3)];
            int qi = 9;
#pragma unroll
            for (int t = 0; t < 9; ++t) {
                acc[t] += v[t];
#pragma unroll
                for (int u = t; u < 9; ++u) acc[qi++] += v[t] * v[u];
            }
        }
        __syncthreads();
    }
    int wv = tid >> 6, lane = tid & 63;
#pragma unroll
    for (int i = 0; i < 54; ++i) {
        float s = acc[i];
        for (int d = 1; d < 64; d <<= 1) s += __shfl_xor(s, d);
        if (lane == 0) red[wv][i] = s;
    }
    __syncthreads();
    if (tid < 54)
        qpart[blockIdx.x * 54 + tid] = red[0][tid] + red[1][tid] + red[2][tid] + red[3][tid];
}

// k2: reduce qpart -> S,Q; per-channel mean/var from 9x9 moments (bias cancels in BN)
__global__ __launch_bounds__(64) void k2_bn1_final(const float* __restrict__ qpart,
                                                   const float* __restrict__ w1,
                                                   const float* __restrict__ g1,
                                                   const float* __restrict__ be1,
                                                   float* __restrict__ sc1,
                                                   float* __restrict__ sh1) {
    __shared__ float T[54];
    int tid = threadIdx.x;
    if (tid < 54) {
        float s = 0.f;
#pragma unroll 8
        for (int b = 0; b < 256; ++b) s += qpart[b * 54 + tid];
        T[tid] = s;
    }
    __syncthreads();
    if (tid < 32) {
        const float inv = 1.f / (4096.f * 784.f);
        float w[9];
#pragma unroll
        for (int t = 0; t < 9; ++t) w[t] = w1[tid * 9 + t];
        float mean = 0.f;
#pragma unroll
        for (int t = 0; t < 9; ++t) mean += w[t] * T[t];
        mean *= inv;
        float ex2 = 0.f;
        int qi = 9;
#pragma unroll
        for (int t = 0; t < 9; ++t)
#pragma unroll
            for (int u = t; u < 9; ++u) {
                float c = w[t] * w[u] * T[qi++];
                ex2 += (u == t) ? c : 2.f * c;
            }
        ex2 *= inv;
        float var = ex2 - mean * mean;
        float a = g1[tid] * rsqrtf(var + EPSBN);
        sc1[tid] = a;
        sh1[tid] = be1[tid] - a * mean;
    }
}

// k34: per image: conv1+BN1+ReLU+pool -> LDS bf16 -> conv2 via MFMA -> stats + pooled max/min
__global__ __launch_bounds__(TPB) void k34_conv2_mfma(const float* __restrict__ x,
                                                      const float* __restrict__ w1,
                                                      const float* __restrict__ sc1,
                                                      const float* __restrict__ sh1,
                                                      const unsigned short* __restrict__ wAg,
                                                      const float* __restrict__ b2,
                                                      float* __restrict__ pmax,
                                                      unsigned short* __restrict__ pminh,
                                                      float* __restrict__ bn2part) {
    __shared__ __align__(16) unsigned short SH[15496];
    float* xs   = (float*)(SH + 13568);
    float* wred = (float*)(SH + 13568);
    float* b2l  = (float*)(SH + 15368);
    float* slab = (float*)SH;

    int tid = threadIdx.x;
    int n   = blockIdx.x;
    int lane = tid & 63, wv = tid >> 6, quad = lane >> 4, l15 = lane & 15;

    for (int i = tid; i < 5120; i += TPB) ((unsigned*)SH)[i] = 0u;
    for (int i = tid; i < 900; i += TPB) xs[i] = 0.f;
    if (tid < 64) b2l[tid] = b2[tid];
    __syncthreads();
    for (int i = tid; i < 784; i += TPB) {
        int r = i / 28, c = i % 28;
        xs[(r + 1) * 30 + (c + 1)] = x[n * 784 + i];
    }
    __syncthreads();

    if (tid < 196) {
        int py = tid / 14, px = tid % 14;
        int paddr = (py + 1) * 16 + (px + 1);
        float patch[4][4];
#pragma unroll
        for (int r = 0; r < 4; ++r)
#pragma unroll
            for (int c = 0; c < 4; ++c) patch[r][c] = xs[(2 * py + r) * 30 + 2 * px + c];
        unsigned hp = 0;
#pragma unroll
        for (int co = 0; co < 32; ++co) {
            float a = sc1[co], cc = sh1[co];
            float m = -1e30f;
#pragma unroll
            for (int sy = 0; sy < 2; ++sy)
#pragma unroll
                for (int sx = 0; sx < 2; ++sx) {
                    float v = 0.f;
#pragma unroll
                    for (int t = 0; t < 9; ++t) v += patch[sy + t / 3][sx + t % 3] * w1[co * 9 + t];
                    m = fmaxf(m, a * v + cc);
                }
            unsigned short h = f2bf(fmaxf(m, 0.f));
            if ((co & 1) == 0) hp = h;
            else ((unsigned*)SH)[(paddr * 40 + co - 1) >> 1] = hp | ((unsigned)h << 16);
        }
    }
    __syncthreads();

    int baseB[4];
    float vmsk[4];
    int pvals[4];
#pragma unroll
    for (int i = 0; i < 4; ++i) {
        int nt = wv + 4 * i;
        int p  = nt * 16 + l15;
        vmsk[i]  = (nt <= 12 && p < 196) ? 1.f : 0.f;
        pvals[i] = p;
        int pc = p < 196 ? p : 195;
        int py = pc / 14, px = pc - py * 14;
        baseB[i] = ((py + 1) * 16 + (px + 1)) * 80 + quad * 16;
    }
    f4v acc[4][4];
#pragma unroll
    for (int i = 0; i < 4; ++i)
#pragma unroll
        for (int mt = 0; mt < 4; ++mt) acc[i][mt] = (f4v){0.f, 0.f, 0.f, 0.f};

    const char* h1hiB = (const char*)SH;
#pragma unroll
    for (int t = 0; t < 9; ++t) {
        const int toff = ((t / 3) - 1) * 1280 + ((t % 3) - 1) * 80;
        bf8v wa0 = *(const bf8v*)(wAg + ((t * 4 + 0) * 64 + lane) * 8);
        bf8v wa1 = *(const bf8v*)(wAg + ((t * 4 + 1) * 64 + lane) * 8);
        bf8v wa2 = *(const bf8v*)(wAg + ((t * 4 + 2) * 64 + lane) * 8);
        bf8v wa3 = *(const bf8v*)(wAg + ((t * 4 + 3) * 64 + lane) * 8);
#pragma unroll
        for (int i = 0; i < 4; ++i) {
            if (wv + 4 * i > 12) continue;
            bf8v bhi = *(const bf8v*)(h1hiB + baseB[i] + toff);
            acc[i][0] = __builtin_amdgcn_mfma_f32_16x16x32_bf16(wa0, bhi, acc[i][0], 0, 0, 0);
            acc[i][1] = __builtin_amdgcn_mfma_f32_16x16x32_bf16(wa1, bhi, acc[i][1], 0, 0, 0);
            acc[i][2] = __builtin_amdgcn_mfma_f32_16x16x32_bf16(wa2, bhi, acc[i][2], 0, 0, 0);
            acc[i][3] = __builtin_amdgcn_mfma_f32_16x16x32_bf16(wa3, bhi, acc[i][3], 0, 0, 0);
        }
    }
    float bb[4][4];
#pragma unroll
    for (int mt = 0; mt < 4; ++mt)
#pragma unroll
        for (int r = 0; r < 4; ++r) bb[mt][r] = b2l[mt * 16 + quad * 4 + r];
#pragma unroll
    for (int i = 0; i < 4; ++i)
#pragma unroll
        for (int mt = 0; mt < 4; ++mt)
#pragma unroll
            for (int r = 0; r < 4; ++r) acc[i][mt][r] += bb[mt][r];
    float ss[4][4], qq[4][4];
#pragma unroll
    for (int mt = 0; mt < 4; ++mt)
#pragma unroll
        for (int r = 0; r < 4; ++r) { ss[mt][r] = 0.f; qq[mt][r] = 0.f; }
#pragma unroll
    for (int i = 0; i < 4; ++i) {
        if (wv + 4 * i > 12) continue;
#pragma unroll
        for (int mt = 0; mt < 4; ++mt)
#pragma unroll
            for (int r = 0; r < 4; ++r) {
                float v = acc[i][mt][r] * vmsk[i];
                ss[mt][r] += v;
                qq[mt][r] += v * acc[i][mt][r] * vmsk[i];
            }
    }
#pragma unroll
    for (int d = 1; d < 16; d <<= 1)
#pragma unroll
        for (int mt = 0; mt < 4; ++mt)
#pragma unroll
            for (int r = 0; r < 4; ++r) {
                ss[mt][r] += __shfl_xor(ss[mt][r], d);
                qq[mt][r] += __shfl_xor(qq[mt][r], d);
            }
    __syncthreads();
    if (l15 == 0) {
#pragma unroll
        for (int mt = 0; mt < 4; ++mt)
#pragma unroll
            for (int r = 0; r < 4; ++r) {
                int co = mt * 16 + quad * 4 + r;
                wred[wv * 64 + co]        = ss[mt][r];
                wred[256 + wv * 64 + co]  = qq[mt][r];
            }
    }
    __syncthreads();
    if (tid < 64) {
        float s = wred[tid] + wred[64 + tid] + wred[128 + tid] + wred[192 + tid];
        float q = wred[256 + tid] + wred[320 + tid] + wred[384 + tid] + wred[448 + tid];
        bn2part[(n * 64 + tid) * 2 + 0] = s;
        bn2part[(n * 64 + tid) * 2 + 1] = q;
    }
#pragma unroll
    for (int c2 = 0; c2 < 2; ++c2) {
        __syncthreads();
#pragma unroll
        for (int mtl = 0; mtl < 2; ++mtl) {
            int mt = c2 * 2 + mtl;
#pragma unroll
            for (int i = 0; i < 4; ++i) {
                if (wv + 4 * i > 12) continue;
                if (vmsk[i] > 0.f) {
#pragma unroll
                    for (int r = 0; r < 4; ++r)
                        slab[(mtl * 16 + quad * 4 + r) * 212 + pvals[i]] = acc[i][mt][r];
                }
            }
        }
        __syncthreads();
        for (int e = tid; e < 1568; e += TPB) {
            int k = e / 49, pp = e % 49;
            int qy = pp / 7, qx = pp % 7;
            int p0 = qy * 28 + qx * 2;
            float v00 = slab[k * 212 + p0];
            float v01 = slab[k * 212 + p0 + 1];
            float v10 = slab[k * 212 + p0 + 14];
            float v11 = slab[k * 212 + p0 + 15];
            float mx = fmaxf(fmaxf(v00, v01), fmaxf(v10, v11));
            float mn = fminf(fminf(v00, v01), fminf(v10, v11));
            size_t o = (size_t)n * 3136 + (c2 * 32 + k) * 49 + pp;
            pmax[o]  = mx;
            pminh[o] = f2bf(mn);
        }
    }
}

// k5: finalize bn2 -> expanded per-fc1-k scale/shift arrays (3136 each)
__global__ __launch_bounds__(TPB) void k5_bn2_final(const float* __restrict__ bn2part,
                                                    const float* __restrict__ g2,
                                                    const float* __restrict__ be2,
                                                    float* __restrict__ sck,
                                                    float* __restrict__ shk) {
    __shared__ float red[TPB][2];
    __shared__ float sAC[2];
    int tid = threadIdx.x, co = blockIdx.x;
    float s = 0.f, q = 0.f;
    for (int i = tid; i < 4096; i += TPB) {
        s += bn2part[(i * 64 + co) * 2 + 0];
        q += bn2part[(i * 64 + co) * 2 + 1];
    }
    red[tid][0] = s; red[tid][1] = q;
    __syncthreads();
    for (int off = TPB / 2; off; off >>= 1) {
        if (tid < off) { red[tid][0] += red[tid + off][0]; red[tid][1] += red[tid + off][1]; }
        __syncthreads();
    }
    if (tid == 0) {
        const float count = 4096.f * 196.f;
        float mean = red[0][0] / count;
        float var  = red[0][1] / count - mean * mean;
        float a    = g2[co] * rsqrtf(var + EPSBN);
        sAC[0] = a;
        sAC[1] = be2[co] - a * mean;
    }
    __syncthreads();
    if (tid < 49) {
        sck[co * 49 + tid] = sAC[0];
        shk[co * 49 + tid] = sAC[1];
    }
}

// k7: fc1 via MFMA. BN2+ReLU fused into A-staging.
__global__ __launch_bounds__(TPB) void k7_fc1_mfma(const float* __restrict__ pmax,
                                                   const unsigned short* __restrict__ pminh,
                                                   const float* __restrict__ sck,
                                                   const float* __restrict__ shk,
                                                   const unsigned short* __restrict__ fwp,
                                                   float* __restrict__ fpart) {
    __shared__ __align__(16) unsigned short K7S[10240];
    unsigned short* Ahi = K7S;
    unsigned short* Alo = K7S + 2560;
    unsigned short* Bsl = K7S + 5120;
    int tid = threadIdx.x;
    int mt = blockIdx.x & 63, ks = blockIdx.x >> 6;
    int m0 = mt * 64;
    int lane = tid & 63, wv = tid >> 6, quad = lane >> 4, l15 = lane & 15;
    f4v acc[8];
#pragma unroll
    for (int i = 0; i < 8; ++i) acc[i] = (f4v){0.f, 0.f, 0.f, 0.f};

    for (int it = 0; it < 14; ++it) {
        int g  = ks * 14 + it;
        int k0 = g * 32;
#pragma unroll
        for (int i = 0; i < 8; ++i) {
            int e  = tid + i * TPB;
            int r  = e >> 5, kk = e & 31;
            int k  = k0 + kk;
            float a = sck[k], c = shk[k];
            size_t src = (size_t)(m0 + r) * 3136 + k;
            float pool = pmax[src];
            if (a < 0.f) pool = bf2f(pminh[src]);
            float v = fmaxf(a * pool + c, 0.f);
            unsigned short h = f2bf(v);
            Ahi[r * 40 + kk] = h;
            Alo[r * 40 + kk] = f2bf(v - bf2f(h));
        }
        {
            const uint4* src = (const uint4*)(fwp + (size_t)g * 4096 + tid * 16);
            uint4 w0 = src[0], w1 = src[1];
            int n = tid >> 1, kk0 = (tid & 1) * 16;
            *(uint4*)(Bsl + n * 40 + kk0)     = w0;
            *(uint4*)(Bsl + n * 40 + kk0 + 8) = w1;
        }
        __syncthreads();
        bf8v ahi = *(const bf8v*)(Ahi + (wv * 16 + l15) * 40 + quad * 8);
        bf8v alo = *(const bf8v*)(Alo + (wv * 16 + l15) * 40 + quad * 8);
#pragma unroll
        for (int nt = 0; nt < 8; ++nt) {
            bf8v b = *(const bf8v*)(Bsl + (nt * 16 + l15) * 40 + quad * 8);
            acc[nt] = __builtin_amdgcn_mfma_f32_16x16x32_bf16(ahi, b, acc[nt], 0, 0, 0);
            acc[nt] = __builtin_amdgcn_mfma_f32_16x16x32_bf16(alo, b, acc[nt], 0, 0, 0);
        }
        __syncthreads();
    }
#pragma unroll
    for (int nt = 0; nt < 8; ++nt)
#pragma unroll
        for (int r = 0; r < 4; ++r) {
            int m = m0 + wv * 16 + quad * 4 + r;
            int nn = nt * 16 + l15;
            fpart[(size_t)ks * 524288 + m * 128 + nn] = acc[nt][r];
        }
}

// k7b: reduce 7 K-split partials + bias + ReLU -> Phi [4096][129]
__global__ __launch_bounds__(TPB) void k7b_relu(const float* __restrict__ fpart,
                                                const float* __restrict__ fb,
                                                float* __restrict__ Phi) {
    int e = blockIdx.x * TPB + threadIdx.x;
    int n = e >> 7, f = e & 127;
    float s = fb[f];
#pragma unroll
    for (int c = 0; c < 7; ++c) s += fpart[(size_t)c * 524288 + e];
    Phi[n * 129 + f] = fmaxf(s, 0.f);
    if (f == 0) Phi[n * 129 + 128] = 1.0f;
}

// k8: partial Gram + C, 32-sample chunks
__global__ __launch_bounds__(TPB) void k8_gram(const float* __restrict__ Phi,
                                               const float* __restrict__ y,
                                               float* __restrict__ Gpart,
                                               float* __restrict__ Cpart) {
    __shared__ __align__(16) float ph[32 * 132];
    __shared__ __align__(16) float yl[32 * 12];
    int tid = threadIdx.x;
    int cB  = blockIdx.x;
    int n0  = cB * 32;
    for (int i = tid; i < 32 * 132; i += TPB) ph[i] = 0.f;
    for (int i = tid; i < 32 * 12; i += TPB) yl[i] = 0.f;
    __syncthreads();
    for (int i = tid; i < 32 * 129; i += TPB) {
        int r = i / 129, d = i % 129;
        ph[r * 132 + d] = Phi[(n0 + r) * 129 + d];
    }
    for (int i = tid; i < 320; i += TPB) {
        int r = i / 10, j = i % 10;
        yl[r * 12 + j] = y[(n0 + r) * 10 + j];
    }
    __syncthreads();
    for (int g = tid; g < 129 * 33; g += TPB) {
        int i = g / 33, j0 = (g % 33) * 4;
        float4 s = make_float4(0.f, 0.f, 0.f, 0.f);
        for (int r = 0; r < 32; ++r) {
            float  vi = ph[r * 132 + i];
            float4 vj = *(const float4*)&ph[r * 132 + j0];
            s.x += vi * vj.x; s.y += vi * vj.y; s.z += vi * vj.z; s.w += vi * vj.w;
        }
        *(float4*)&Gpart[(size_t)cB * 17028 + i * 132 + j0] = s;
    }
    for (int g = tid; g < 129 * 3; g += TPB) {
        int i = g / 3, j0 = (g % 3) * 4;
        float4 s = make_float4(0.f, 0.f, 0.f, 0.f);
        for (int r = 0; r < 32; ++r) {
            float  vi = ph[r * 132 + i];
            float4 vj = *(const float4*)&yl[r * 12 + j0];
            s.x += vi * vj.x; s.y += vi * vj.y; s.z += vi * vj.z; s.w += vi * vj.w;
        }
        *(float4*)&Cpart[(size_t)cB * 1548 + i * 12 + j0] = s;
    }
}

// k9: reduce partials -> G [129*129], C [129*10]
__global__ __launch_bounds__(TPB) void k9_reduce(const float* __restrict__ Gpart,
                                                 const float* __restrict__ Cpart,
                                                 float* __restrict__ G,
                                                 float* __restrict__ C) {
    int e = blockIdx.x * TPB + threadIdx.x;
    if (e < 16641) {
        int i = e / 129, j = e % 129;
        float s = 0.f;
        for (int c = 0; c < 128; ++c) s += Gpart[(size_t)c * 17028 + i * 132 + j];
        G[e] = s;
    } else if (e < 16641 + 1290) {
        int e2 = e - 16641;
        int i = e2 / 10, j = e2 % 10;
        float s = 0.f;
        for (int c = 0; c < 128; ++c) s += Cpart[(size_t)c * 1548 + i * 12 + j];
        C[e2] = s;
    }
}

// k10: solve (I+G) W = W0 + C. Blocked GE, PW=16, 1024 threads (16 waves on one CU
// for latency hiding — r10 showed the 256-thread version ~90% stalled):
//  A) 16x16 diag factor in registers (wave 0 lanes 0..15, shfl)
//  B) L21 row-parallel TRSM on tids 0..127  } run CONCURRENTLY (disjoint LpT/M regions,
//  C) U12 column-parallel on tids 128+      } no barrier between them)
//  D) trailing rank-16 update, 4x4 b128 register tiles, all 1024 threads
//  back-sub: register-resident RHS on wave 0, shfl broadcast.
__global__ __launch_bounds__(TPBS) void k10_solve(const float* __restrict__ G,
                                                  const float* __restrict__ C,
                                                  const float* __restrict__ W0,
                                                  float* __restrict__ Wnew) {
    __shared__ __align__(16) float M[129 * 140];
    __shared__ __align__(16) float LpT[PW * 132];   // [k][r], per-panel
    __shared__ float invD[129];
    int tid = threadIdx.x;
    int lane = tid & 63, wv = tid >> 6;
    for (int e = tid; e < 129 * 129; e += TPBS) {
        int i = e / 129, j = e % 129;
        M[i * 140 + j] = G[e] + (i == j ? 1.f : 0.f);
    }
    for (int i = tid; i < 129; i += TPBS) M[i * 140 + 129] = 0.f;
    for (int e = tid; e < 1290; e += TPBS) {
        int i = e / 10, c = e % 10;
        M[i * 140 + 130 + c] = W0[e] + C[e];
    }
    __syncthreads();

    for (int k0 = 0; k0 < 128; k0 += PW) {
        const int kend = k0 + PW;
        // --- A: 16x16 diagonal factor in registers (wave 0, lanes 0..15) ---
        if (wv == 0) {
            bool act = lane < PW;
            int r  = k0 + lane;
            int rc = act ? r : k0;
            float u[PW], Lr[PW];
#pragma unroll
            for (int j = 0; j < PW; ++j) u[j] = M[rc * 140 + k0 + j];
            float dval = u[0];
#pragma unroll
            for (int k = 0; k < PW; ++k) {
                if (lane == k) dval = u[k];
                float piv = __shfl(u[k], k);
                float f   = u[k] / piv;
                float fm  = (act && lane > k) ? f : 0.f;
                Lr[k] = fm;
#pragma unroll
                for (int j = 0; j < PW; ++j)
                    if (j > k) u[j] -= fm * __shfl(u[j], k);
            }
            if (act) {
#pragma unroll
                for (int j = 0; j < PW; ++j)
                    if (j >= lane) M[r * 140 + k0 + j] = u[j];
#pragma unroll
                for (int k = 0; k < PW; ++k)
                    if (k < lane) LpT[k * 132 + r] = Lr[k];
                invD[r] = 1.f / dval;
            }
        }
        __syncthreads();
        // --- B (tids 0..127): L21 TRSM row-parallel -> LpT rows >= kend ---
        if (tid < 128) {
            int r = kend + tid;
            if (r <= 128) {
                float a[PW], l[PW];
                float4 a4[4];
#pragma unroll
                for (int q = 0; q < 4; ++q) a4[q] = *(const float4*)&M[r * 140 + k0 + q * 4];
#pragma unroll
                for (int q = 0; q < 4; ++q) {
                    a[q * 4 + 0] = a4[q].x; a[q * 4 + 1] = a4[q].y;
                    a[q * 4 + 2] = a4[q].z; a[q * 4 + 3] = a4[q].w;
                }
#pragma unroll
                for (int k = 0; k < PW; ++k) {
                    float v = a[k];
#pragma unroll
                    for (int m = 0; m < PW; ++m)
                        if (m < k) v -= l[m] * M[(k0 + m) * 140 + k0 + k];
                    l[k] = v * invD[k0 + k];
                    LpT[k * 132 + r] = l[k];
                }
            }
        } else {
            // --- C (tids 128+): U12 := L11^{-1} U12 (cols kend..139 incl. RHS) ---
            // reads only LpT panel rows written by A — disjoint from B's writes
            for (int j = kend + (tid - 128); j < 140; j += (TPBS - 128)) {
                float u[PW];
#pragma unroll
                for (int kk = 0; kk < PW; ++kk) {
                    float v = M[(k0 + kk) * 140 + j];
#pragma unroll
                    for (int m = 0; m < PW; ++m)
                        if (m < kk) v -= LpT[m * 132 + k0 + kk] * u[m];
                    u[kk] = v;
                    M[(k0 + kk) * 140 + j] = v;
                }
            }
        }
        __syncthreads();
        // --- D: trailing rank-16 update, 4 rows x 4 cols per task, b128 everywhere ---
        const int R = 129 - kend, Jn = 140 - kend;
        const int nrt = (R + 3) >> 2, nct = (Jn + 3) >> 2;
        for (int t = tid; t < nrt * nct; t += TPBS) {
            int tr = t % nrt, tc = t / nrt;
            int r0 = kend + tr * 4;
            int j0 = kend + tc * 4;
            float4 s0 = {0, 0, 0, 0}, s1 = {0, 0, 0, 0}, s2 = {0, 0, 0, 0}, s3 = {0, 0, 0, 0};
#pragma unroll
            for (int kk = 0; kk < PW; ++kk) {
                float4 L4 = *(const float4*)&LpT[kk * 132 + r0];
                float4 U4 = *(const float4*)&M[(k0 + kk) * 140 + j0];
                s0.x += L4.x * U4.x; s0.y += L4.x * U4.y; s0.z += L4.x * U4.z; s0.w += L4.x * U4.w;
                s1.x += L4.y * U4.x; s1.y += L4.y * U4.y; s1.z += L4.y * U4.z; s1.w += L4.y * U4.w;
                s2.x += L4.z * U4.x; s2.y += L4.z * U4.y; s2.z += L4.z * U4.z; s2.w += L4.z * U4.w;
                s3.x += L4.w * U4.x; s3.y += L4.w * U4.y; s3.z += L4.w * U4.z; s3.w += L4.w * U4.w;
            }
            float4 sv[4] = {s0, s1, s2, s3};
#pragma unroll
            for (int i = 0; i < 4; ++i) {
                int r = r0 + i;
                if (r <= 128) {
                    float4 mv = *(const float4*)&M[r * 140 + j0];
                    mv.x -= sv[i].x; mv.y -= sv[i].y; mv.z -= sv[i].z; mv.w -= sv[i].w;
                    *(float4*)&M[r * 140 + j0] = mv;
                }
            }
        }
        __syncthreads();
    }
    if (tid == 0) invD[128] = 1.f / M[128 * 140 + 128];
    __syncthreads();
    // --- back substitution: RHS register-resident on wave 0, shfl broadcast ---
    if (wv == 0) {
        int r0 = lane, r1 = lane + 64;
        float b0[10], b1[10], b2[10];
#pragma unroll
        for (int c = 0; c < 10; ++c) {
            b0[c] = M[r0 * 140 + 130 + c];
            b1[c] = M[r1 * 140 + 130 + c];
            b2[c] = (lane == 0) ? M[128 * 140 + 130 + c] : 0.f;
        }
        float id0 = invD[r0], id1 = invD[r1];
        float id2 = (lane == 0) ? invD[128] : 0.f;
        for (int k = 128; k >= 0; --k) {
            int src = k & 63, slot = k >> 6;
            if (lane == src) {
                if (slot == 2) {
#pragma unroll
                    for (int c = 0; c < 10; ++c) b2[c] *= id2;
                } else if (slot == 1) {
#pragma unroll
                    for (int c = 0; c < 10; ++c) b1[c] *= id1;
                } else {
#pragma unroll
                    for (int c = 0; c < 10; ++c) b0[c] *= id0;
                }
            }
            float m0 = (r0 < k) ? M[r0 * 140 + k] : 0.f;
            float m1 = (r1 < k) ? M[r1 * 140 + k] : 0.f;
#pragma unroll
            for (int c = 0; c < 10; ++c) {
                float v = (slot == 2) ? b2[c] : (slot == 1 ? b1[c] : b0[c]);
                float xc = __shfl(v, src);
                b0[c] -= m0 * xc;
                b1[c] -= m1 * xc;
            }
        }
#pragma unroll
        for (int c = 0; c < 10; ++c) {
            Wnew[r0 * 10 + c] = b0[c];
            Wnew[r1 * 10 + c] = b1[c];
            if (lane == 0) Wnew[1280 + c] = b2[c];
        }
    }
}

// k11: out = Phi @ Wnew  ([4096][10])
__global__ __launch_bounds__(TPB) void k11_out(const float* __restrict__ Phi,
                                               const float* __restrict__ Wnew,
                                               float* __restrict__ out) {
    __shared__ float Wl[1290];
    int tid = threadIdx.x;
    for (int i = tid; i < 1290; i += TPB) Wl[i] = Wnew[i];
    __syncthreads();
    int idx = blockIdx.x * TPB + tid;
    int n = idx / 10, j = idx % 10;
    float s = 0.f;
    for (int d = 0; d < 129; ++d) s += Phi[n * 129 + d] * Wl[d * 10 + j];
    out[idx] = s;
}

extern "C" void kernel_launch(void* const* d_in, const int* in_sizes, int n_in,
                              void* d_out, int out_size, void* d_ws, size_t ws_size,
                              hipStream_t stream) {
    const float* x   = (const float*)d_in[0];
    const float* y   = (const float*)d_in[1];
    const float* w1  = (const float*)d_in[2];
    const float* g1  = (const float*)d_in[4];
    const float* be1 = (const float*)d_in[5];
    const float* w2  = (const float*)d_in[6];
    const float* b2  = (const float*)d_in[7];
    const float* g2  = (const float*)d_in[8];
    const float* be2 = (const float*)d_in[9];
    const float* fw  = (const float*)d_in[10];
    const float* fb  = (const float*)d_in[11];
    const float* W0  = (const float*)d_in[12];
    float* out = (float*)d_out;
    float* ws  = (float*)d_ws;
    if (ws_size < WS_TOTAL * 4ull) return;

    unsigned* wAg_u = (unsigned*)(ws + WS_WAG);
    unsigned* fwp_u = (unsigned*)(ws + WS_FWP);
    const unsigned short* wAg_h = (const unsigned short*)wAg_u;
    const unsigned short* fwp_h = (const unsigned short*)fwp_u;
    float* sc1     = ws + WS_SC1;
    float* sh1     = ws + WS_SH1;
    float* sck     = ws + WS_SCK;
    float* shk     = ws + WS_SHK;
    float* G       = ws + WS_G;
    float* C       = ws + WS_C;
    float* Wnew    = ws + WS_WNEW;
    float* qpart   = ws + WS_BN1PART;
    float* bn2part = ws + WS_BN2PART;
    float* Phi     = ws + WS_PHI;
    float* fpart   = ws + WS_FPART;
    float* Gpart   = ws + WS_GPART;
    float* Cpart   = ws + WS_CPART;
    float* pmax    = ws + WS_PMAX;
    unsigned short* pminh = (unsigned short*)(ws + WS_PMINH);

    kW_pack<<<820, TPB, 0, stream>>>(w2, fw, wAg_u, fwp_u);
    k1_conv1_stats<<<256, TPB, 0, stream>>>(x, qpart);
    k2_bn1_final<<<1, 64, 0, stream>>>(qpart, w1, g1, be1, sc1, sh1);
    k34_conv2_mfma<<<4096, TPB, 0, stream>>>(x, w1, sc1, sh1, wAg_h, b2, pmax, pminh, bn2part);
    k5_bn2_final<<<64, TPB, 0, stream>>>(bn2part, g2, be2, sck, shk);
    k7_fc1_mfma<<<448, TPB, 0, stream>>>(pmax, pminh, sck, shk, fwp_h, fpart);
    k7b_relu<<<2048, TPB, 0, stream>>>(fpart, fb, Phi);
    k8_gram<<<128, TPB, 0, stream>>>(Phi, y, Gpart, Cpart);
    k9_reduce<<<71, TPB, 0, stream>>>(Gpart, Cpart, G, C);
    k10_solve<<<1, TPBS, 0, stream>>>(G, C, W0, Wnew);
    k11_out<<<160, TPB, 0, stream>>>(Phi, Wnew, out);
}

// Round 12
// 479.173 us; speedup vs baseline: 1.0248x; 1.0248x over previous
//
#include <hip/hip_runtime.h>
#include <math.h>

#define TPB 256
#define EPSBN 1e-5f
#define PW 16

typedef __attribute__((ext_vector_type(8))) short bf8v;   // 8 x bf16 (4 VGPR)
typedef __attribute__((ext_vector_type(4))) float f4v;    // MFMA acc

static __device__ __forceinline__ unsigned short f2bf(float f) {
    union { float f; unsigned u; } v; v.f = f;
    unsigned r = v.u + 0x7fffu + ((v.u >> 16) & 1u);
    return (unsigned short)(r >> 16);
}
static __device__ __forceinline__ float bf2f(unsigned short h) {
    union { unsigned u; float f; } v; v.u = ((unsigned)h) << 16;
    return v.f;
}

// ---- workspace layout (float element offsets); total 26,865,664 floats (~107.5 MB) ----
#define WS_WAG      0u
#define WS_FWP      9216u
#define WS_SC1      209920u
#define WS_SH1      209952u
#define WS_SCK      209984u
#define WS_SHK      213120u
#define WS_G        216256u
#define WS_C        232897u
#define WS_WNEW     234187u
#define WS_BN1PART  235520u
#define WS_BN2PART  497664u
#define WS_PHI      1021952u
#define WS_FPART    1550336u
#define WS_GPART    5220352u
#define WS_CPART    7399936u
#define WS_PMAX     7598080u
#define WS_PMINH    20443136u
#define WS_TOTAL    26865664ull

// kW: pack conv2 weights into A-frag order (bf16) and fc1 weights into B-frag order (bf16)
__global__ __launch_bounds__(TPB) void kW_pack(const float* __restrict__ w2,
                                               const float* __restrict__ fw,
                                               unsigned* __restrict__ wAg_u,
                                               unsigned* __restrict__ fwp_u) {
    int e = blockIdx.x * TPB + threadIdx.x;
    if (e < 9216) {
        int jj = e & 3, lane = (e >> 2) & 63, mt = (e >> 8) & 3, t = e >> 10;
        int j0 = jj * 2;
        int co = mt * 16 + (lane & 15);
        int ci = (lane >> 4) * 8 + j0;
        unsigned h0 = f2bf(w2[(co * 32 + ci) * 9 + t]);
        unsigned h1 = f2bf(w2[(co * 32 + ci + 1) * 9 + t]);
        wAg_u[e] = h0 | (h1 << 16);
    } else if (e < 9216 + 200704) {
        int f = e - 9216;
        int kk = (f & 15) * 2, n = (f >> 4) & 127, g = f >> 11;
        unsigned h0 = f2bf(fw[n * 3136 + g * 32 + kk]);
        unsigned h1 = f2bf(fw[n * 3136 + g * 32 + kk + 1]);
        fwp_u[f] = h0 | (h1 << 16);
    }
}

// k1: BN1 stats via channel-independent patch moments S[9], Q[45].
__global__ __launch_bounds__(TPB) void k1_conv1_stats(const float* __restrict__ x,
                                                      float* __restrict__ qpart) {
    __shared__ float xs[900];
    __shared__ float red[4][54];
    int tid = threadIdx.x;
    float acc[54];
#pragma unroll
    for (int i = 0; i < 54; ++i) acc[i] = 0.f;
    for (int img = 0; img < 16; ++img) {
        int n = blockIdx.x * 16 + img;
        for (int i = tid; i < 900; i += TPB) xs[i] = 0.f;
        __syncthreads();
        for (int i = tid; i < 784; i += TPB) {
            int r = i / 28, c = i % 28;
            xs[(r + 1) * 30 + (c + 1)] = x[n * 784 + i];
        }
        __syncthreads();
        for (int p = tid; p < 784; p += TPB) {
            int oy = p / 28, ox = p % 28;
            float v[9];
#pragma unroll
            for (int t = 0; t < 9; ++t) v[t] = xs[(oy + t / 3) * 30 + ox + (t % 3)];
            int qi = 9;
#pragma unroll
            for (int t = 0; t < 9; ++t) {
                acc[t] += v[t];
#pragma unroll
                for (int u = t; u < 9; ++u) acc[qi++] += v[t] * v[u];
            }
        }
        __syncthreads();
    }
    int wv = tid >> 6, lane = tid & 63;
#pragma unroll
    for (int i = 0; i < 54; ++i) {
        float s = acc[i];
        for (int d = 1; d < 64; d <<= 1) s += __shfl_xor(s, d);
        if (lane == 0) red[wv][i] = s;
    }
    __syncthreads();
    if (tid < 54)
        qpart[blockIdx.x * 54 + tid] = red[0][tid] + red[1][tid] + red[2][tid] + red[3][tid];
}

// k2: reduce qpart -> S,Q; per-channel mean/var from 9x9 moments (bias cancels in BN)
__global__ __launch_bounds__(64) void k2_bn1_final(const float* __restrict__ qpart,
                                                   const float* __restrict__ w1,
                                                   const float* __restrict__ g1,
                                                   const float* __restrict__ be1,
                                                   float* __restrict__ sc1,
                                                   float* __restrict__ sh1) {
    __shared__ float T[54];
    int tid = threadIdx.x;
    if (tid < 54) {
        float s = 0.f;
#pragma unroll 8
        for (int b = 0; b < 256; ++b) s += qpart[b * 54 + tid];
        T[tid] = s;
    }
    __syncthreads();
    if (tid < 32) {
        const float inv = 1.f / (4096.f * 784.f);
        float w[9];
#pragma unroll
        for (int t = 0; t < 9; ++t) w[t] = w1[tid * 9 + t];
        float mean = 0.f;
#pragma unroll
        for (int t = 0; t < 9; ++t) mean += w[t] * T[t];
        mean *= inv;
        float ex2 = 0.f;
        int qi = 9;
#pragma unroll
        for (int t = 0; t < 9; ++t)
#pragma unroll
            for (int u = t; u < 9; ++u) {
                float c = w[t] * w[u] * T[qi++];
                ex2 += (u == t) ? c : 2.f * c;
            }
        ex2 *= inv;
        float var = ex2 - mean * mean;
        float a = g1[tid] * rsqrtf(var + EPSBN);
        sc1[tid] = a;
        sh1[tid] = be1[tid] - a * mean;
    }
}

// k34: per image: conv1+BN1+ReLU+pool -> LDS bf16 -> conv2 via MFMA -> stats + pooled max/min
__global__ __launch_bounds__(TPB) void k34_conv2_mfma(const float* __restrict__ x,
                                                      const float* __restrict__ w1,
                                                      const float* __restrict__ sc1,
                                                      const float* __restrict__ sh1,
                                                      const unsigned short* __restrict__ wAg,
                                                      const float* __restrict__ b2,
                                                      float* __restrict__ pmax,
                                                      unsigned short* __restrict__ pminh,
                                                      float* __restrict__ bn2part) {
    __shared__ __align__(16) unsigned short SH[15496];
    float* xs   = (float*)(SH + 13568);
    float* wred = (float*)(SH + 13568);
    float* b2l  = (float*)(SH + 15368);
    float* slab = (float*)SH;

    int tid = threadIdx.x;
    int n   = blockIdx.x;
    int lane = tid & 63, wv = tid >> 6, quad = lane >> 4, l15 = lane & 15;

    for (int i = tid; i < 5120; i += TPB) ((unsigned*)SH)[i] = 0u;
    for (int i = tid; i < 900; i += TPB) xs[i] = 0.f;
    if (tid < 64) b2l[tid] = b2[tid];
    __syncthreads();
    for (int i = tid; i < 784; i += TPB) {
        int r = i / 28, c = i % 28;
        xs[(r + 1) * 30 + (c + 1)] = x[n * 784 + i];
    }
    __syncthreads();

    if (tid < 196) {
        int py = tid / 14, px = tid % 14;
        int paddr = (py + 1) * 16 + (px + 1);
        float patch[4][4];
#pragma unroll
        for (int r = 0; r < 4; ++r)
#pragma unroll
            for (int c = 0; c < 4; ++c) patch[r][c] = xs[(2 * py + r) * 30 + 2 * px + c];
        unsigned hp = 0;
#pragma unroll
        for (int co = 0; co < 32; ++co) {
            float a = sc1[co], cc = sh1[co];
            float m = -1e30f;
#pragma unroll
            for (int sy = 0; sy < 2; ++sy)
#pragma unroll
                for (int sx = 0; sx < 2; ++sx) {
                    float v = 0.f;
#pragma unroll
                    for (int t = 0; t < 9; ++t) v += patch[sy + t / 3][sx + t % 3] * w1[co * 9 + t];
                    m = fmaxf(m, a * v + cc);
                }
            unsigned short h = f2bf(fmaxf(m, 0.f));
            if ((co & 1) == 0) hp = h;
            else ((unsigned*)SH)[(paddr * 40 + co - 1) >> 1] = hp | ((unsigned)h << 16);
        }
    }
    __syncthreads();

    int baseB[4];
    float vmsk[4];
    int pvals[4];
#pragma unroll
    for (int i = 0; i < 4; ++i) {
        int nt = wv + 4 * i;
        int p  = nt * 16 + l15;
        vmsk[i]  = (nt <= 12 && p < 196) ? 1.f : 0.f;
        pvals[i] = p;
        int pc = p < 196 ? p : 195;
        int py = pc / 14, px = pc - py * 14;
        baseB[i] = ((py + 1) * 16 + (px + 1)) * 80 + quad * 16;
    }
    f4v acc[4][4];
#pragma unroll
    for (int i = 0; i < 4; ++i)
#pragma unroll
        for (int mt = 0; mt < 4; ++mt) acc[i][mt] = (f4v){0.f, 0.f, 0.f, 0.f};

    const char* h1hiB = (const char*)SH;
#pragma unroll
    for (int t = 0; t < 9; ++t) {
        const int toff = ((t / 3) - 1) * 1280 + ((t % 3) - 1) * 80;
        bf8v wa0 = *(const bf8v*)(wAg + ((t * 4 + 0) * 64 + lane) * 8);
        bf8v wa1 = *(const bf8v*)(wAg + ((t * 4 + 1) * 64 + lane) * 8);
        bf8v wa2 = *(const bf8v*)(wAg + ((t * 4 + 2) * 64 + lane) * 8);
        bf8v wa3 = *(const bf8v*)(wAg + ((t * 4 + 3) * 64 + lane) * 8);
#pragma unroll
        for (int i = 0; i < 4; ++i) {
            if (wv + 4 * i > 12) continue;
            bf8v bhi = *(const bf8v*)(h1hiB + baseB[i] + toff);
            acc[i][0] = __builtin_amdgcn_mfma_f32_16x16x32_bf16(wa0, bhi, acc[i][0], 0, 0, 0);
            acc[i][1] = __builtin_amdgcn_mfma_f32_16x16x32_bf16(wa1, bhi, acc[i][1], 0, 0, 0);
            acc[i][2] = __builtin_amdgcn_mfma_f32_16x16x32_bf16(wa2, bhi, acc[i][2], 0, 0, 0);
            acc[i][3] = __builtin_amdgcn_mfma_f32_16x16x32_bf16(wa3, bhi, acc[i][3], 0, 0, 0);
        }
    }
    float bb[4][4];
#pragma unroll
    for (int mt = 0; mt < 4; ++mt)
#pragma unroll
        for (int r = 0; r < 4; ++r) bb[mt][r] = b2l[mt * 16 + quad * 4 + r];
#pragma unroll
    for (int i = 0; i < 4; ++i)
#pragma unroll
        for (int mt = 0; mt < 4; ++mt)
#pragma unroll
            for (int r = 0; r < 4; ++r) acc[i][mt][r] += bb[mt][r];
    float ss[4][4], qq[4][4];
#pragma unroll
    for (int mt = 0; mt < 4; ++mt)
#pragma unroll
        for (int r = 0; r < 4; ++r) { ss[mt][r] = 0.f; qq[mt][r] = 0.f; }
#pragma unroll
    for (int i = 0; i < 4; ++i) {
        if (wv + 4 * i > 12) continue;
#pragma unroll
        for (int mt = 0; mt < 4; ++mt)
#pragma unroll
            for (int r = 0; r < 4; ++r) {
                float v = acc[i][mt][r] * vmsk[i];
                ss[mt][r] += v;
                qq[mt][r] += v * acc[i][mt][r] * vmsk[i];
            }
    }
#pragma unroll
    for (int d = 1; d < 16; d <<= 1)
#pragma unroll
        for (int mt = 0; mt < 4; ++mt)
#pragma unroll
            for (int r = 0; r < 4; ++r) {
                ss[mt][r] += __shfl_xor(ss[mt][r], d);
                qq[mt][r] += __shfl_xor(qq[mt][r], d);
            }
    __syncthreads();
    if (l15 == 0) {
#pragma unroll
        for (int mt = 0; mt < 4; ++mt)
#pragma unroll
            for (int r = 0; r < 4; ++r) {
                int co = mt * 16 + quad * 4 + r;
                wred[wv * 64 + co]        = ss[mt][r];
                wred[256 + wv * 64 + co]  = qq[mt][r];
            }
    }
    __syncthreads();
    if (tid < 64) {
        float s = wred[tid] + wred[64 + tid] + wred[128 + tid] + wred[192 + tid];
        float q = wred[256 + tid] + wred[320 + tid] + wred[384 + tid] + wred[448 + tid];
        bn2part[(n * 64 + tid) * 2 + 0] = s;
        bn2part[(n * 64 + tid) * 2 + 1] = q;
    }
#pragma unroll
    for (int c2 = 0; c2 < 2; ++c2) {
        __syncthreads();
#pragma unroll
        for (int mtl = 0; mtl < 2; ++mtl) {
            int mt = c2 * 2 + mtl;
#pragma unroll
            for (int i = 0; i < 4; ++i) {
                if (wv + 4 * i > 12) continue;
                if (vmsk[i] > 0.f) {
#pragma unroll
                    for (int r = 0; r < 4; ++r)
                        slab[(mtl * 16 + quad * 4 + r) * 212 + pvals[i]] = acc[i][mt][r];
                }
            }
        }
        __syncthreads();
        for (int e = tid; e < 1568; e += TPB) {
            int k = e / 49, pp = e % 49;
            int qy = pp / 7, qx = pp % 7;
            int p0 = qy * 28 + qx * 2;
            float v00 = slab[k * 212 + p0];
            float v01 = slab[k * 212 + p0 + 1];
            float v10 = slab[k * 212 + p0 + 14];
            float v11 = slab[k * 212 + p0 + 15];
            float mx = fmaxf(fmaxf(v00, v01), fmaxf(v10, v11));
            float mn = fminf(fminf(v00, v01), fminf(v10, v11));
            size_t o = (size_t)n * 3136 + (c2 * 32 + k) * 49 + pp;
            pmax[o]  = mx;
            pminh[o] = f2bf(mn);
        }
    }
}

// k5: finalize bn2 -> expanded per-fc1-k scale/shift arrays (3136 each)
__global__ __launch_bounds__(TPB) void k5_bn2_final(const float* __restrict__ bn2part,
                                                    const float* __restrict__ g2,
                                                    const float* __restrict__ be2,
                                                    float* __restrict__ sck,
                                                    float* __restrict__ shk) {
    __shared__ float red[TPB][2];
    __shared__ float sAC[2];
    int tid = threadIdx.x, co = blockIdx.x;
    float s = 0.f, q = 0.f;
    for (int i = tid; i < 4096; i += TPB) {
        s += bn2part[(i * 64 + co) * 2 + 0];
        q += bn2part[(i * 64 + co) * 2 + 1];
    }
    red[tid][0] = s; red[tid][1] = q;
    __syncthreads();
    for (int off = TPB / 2; off; off >>= 1) {
        if (tid < off) { red[tid][0] += red[tid + off][0]; red[tid][1] += red[tid + off][1]; }
        __syncthreads();
    }
    if (tid == 0) {
        const float count = 4096.f * 196.f;
        float mean = red[0][0] / count;
        float var  = red[0][1] / count - mean * mean;
        float a    = g2[co] * rsqrtf(var + EPSBN);
        sAC[0] = a;
        sAC[1] = be2[co] - a * mean;
    }
    __syncthreads();
    if (tid < 49) {
        sck[co * 49 + tid] = sAC[0];
        shk[co * 49 + tid] = sAC[1];
    }
}

// k7: fc1 via MFMA, single-bf16 activations (lo-split dropped — conv2 lo-drop was
// absmax-neutral in r9; same error class here). BN2+ReLU fused into A-staging.
__global__ __launch_bounds__(TPB) void k7_fc1_mfma(const float* __restrict__ pmax,
                                                   const unsigned short* __restrict__ pminh,
                                                   const float* __restrict__ sck,
                                                   const float* __restrict__ shk,
                                                   const unsigned short* __restrict__ fwp,
                                                   float* __restrict__ fpart) {
    __shared__ __align__(16) unsigned short K7S[7680];   // Ahi[64*40] Bsl[128*40]
    unsigned short* Ahi = K7S;
    unsigned short* Bsl = K7S + 2560;
    int tid = threadIdx.x;
    int mt = blockIdx.x & 63, ks = blockIdx.x >> 6;
    int m0 = mt * 64;
    int lane = tid & 63, wv = tid >> 6, quad = lane >> 4, l15 = lane & 15;
    f4v acc[8];
#pragma unroll
    for (int i = 0; i < 8; ++i) acc[i] = (f4v){0.f, 0.f, 0.f, 0.f};

    for (int it = 0; it < 14; ++it) {
        int g  = ks * 14 + it;
        int k0 = g * 32;
#pragma unroll
        for (int i = 0; i < 8; ++i) {
            int e  = tid + i * TPB;
            int r  = e >> 5, kk = e & 31;
            int k  = k0 + kk;
            float a = sck[k], c = shk[k];
            size_t src = (size_t)(m0 + r) * 3136 + k;
            float pool = pmax[src];
            if (a < 0.f) pool = bf2f(pminh[src]);
            float v = fmaxf(a * pool + c, 0.f);
            Ahi[r * 40 + kk] = f2bf(v);
        }
        {
            const uint4* src = (const uint4*)(fwp + (size_t)g * 4096 + tid * 16);
            uint4 w0 = src[0], w1 = src[1];
            int n = tid >> 1, kk0 = (tid & 1) * 16;
            *(uint4*)(Bsl + n * 40 + kk0)     = w0;
            *(uint4*)(Bsl + n * 40 + kk0 + 8) = w1;
        }
        __syncthreads();
        bf8v ahi = *(const bf8v*)(Ahi + (wv * 16 + l15) * 40 + quad * 8);
#pragma unroll
        for (int nt = 0; nt < 8; ++nt) {
            bf8v b = *(const bf8v*)(Bsl + (nt * 16 + l15) * 40 + quad * 8);
            acc[nt] = __builtin_amdgcn_mfma_f32_16x16x32_bf16(ahi, b, acc[nt], 0, 0, 0);
        }
        __syncthreads();
    }
#pragma unroll
    for (int nt = 0; nt < 8; ++nt)
#pragma unroll
        for (int r = 0; r < 4; ++r) {
            int m = m0 + wv * 16 + quad * 4 + r;
            int nn = nt * 16 + l15;
            fpart[(size_t)ks * 524288 + m * 128 + nn] = acc[nt][r];
        }
}

// k7b: reduce 7 K-split partials + bias + ReLU -> Phi [4096][129]
__global__ __launch_bounds__(TPB) void k7b_relu(const float* __restrict__ fpart,
                                                const float* __restrict__ fb,
                                                float* __restrict__ Phi) {
    int e = blockIdx.x * TPB + threadIdx.x;
    int n = e >> 7, f = e & 127;
    float s = fb[f];
#pragma unroll
    for (int c = 0; c < 7; ++c) s += fpart[(size_t)c * 524288 + e];
    Phi[n * 129 + f] = fmaxf(s, 0.f);
    if (f == 0) Phi[n * 129 + 128] = 1.0f;
}

// k8: partial Gram + C, 32-sample chunks
__global__ __launch_bounds__(TPB) void k8_gram(const float* __restrict__ Phi,
                                               const float* __restrict__ y,
                                               float* __restrict__ Gpart,
                                               float* __restrict__ Cpart) {
    __shared__ __align__(16) float ph[32 * 132];
    __shared__ __align__(16) float yl[32 * 12];
    int tid = threadIdx.x;
    int cB  = blockIdx.x;
    int n0  = cB * 32;
    for (int i = tid; i < 32 * 132; i += TPB) ph[i] = 0.f;
    for (int i = tid; i < 32 * 12; i += TPB) yl[i] = 0.f;
    __syncthreads();
    for (int i = tid; i < 32 * 129; i += TPB) {
        int r = i / 129, d = i % 129;
        ph[r * 132 + d] = Phi[(n0 + r) * 129 + d];
    }
    for (int i = tid; i < 320; i += TPB) {
        int r = i / 10, j = i % 10;
        yl[r * 12 + j] = y[(n0 + r) * 10 + j];
    }
    __syncthreads();
    for (int g = tid; g < 129 * 33; g += TPB) {
        int i = g / 33, j0 = (g % 33) * 4;
        float4 s = make_float4(0.f, 0.f, 0.f, 0.f);
        for (int r = 0; r < 32; ++r) {
            float  vi = ph[r * 132 + i];
            float4 vj = *(const float4*)&ph[r * 132 + j0];
            s.x += vi * vj.x; s.y += vi * vj.y; s.z += vi * vj.z; s.w += vi * vj.w;
        }
        *(float4*)&Gpart[(size_t)cB * 17028 + i * 132 + j0] = s;
    }
    for (int g = tid; g < 129 * 3; g += TPB) {
        int i = g / 3, j0 = (g % 3) * 4;
        float4 s = make_float4(0.f, 0.f, 0.f, 0.f);
        for (int r = 0; r < 32; ++r) {
            float  vi = ph[r * 132 + i];
            float4 vj = *(const float4*)&yl[r * 12 + j0];
            s.x += vi * vj.x; s.y += vi * vj.y; s.z += vi * vj.z; s.w += vi * vj.w;
        }
        *(float4*)&Cpart[(size_t)cB * 1548 + i * 12 + j0] = s;
    }
}

// k9: reduce partials -> G [129*129], C [129*10]
__global__ __launch_bounds__(TPB) void k9_reduce(const float* __restrict__ Gpart,
                                                 const float* __restrict__ Cpart,
                                                 float* __restrict__ G,
                                                 float* __restrict__ C) {
    int e = blockIdx.x * TPB + threadIdx.x;
    if (e < 16641) {
        int i = e / 129, j = e % 129;
        float s = 0.f;
        for (int c = 0; c < 128; ++c) s += Gpart[(size_t)c * 17028 + i * 132 + j];
        G[e] = s;
    } else if (e < 16641 + 1290) {
        int e2 = e - 16641;
        int i = e2 / 10, j = e2 % 10;
        float s = 0.f;
        for (int c = 0; c < 128; ++c) s += Cpart[(size_t)c * 1548 + i * 12 + j];
        C[e2] = s;
    }
}

// k10: solve (I+G) W = W0 + C. Blocked GE, PW=16, 256 threads — frozen at the best
// measured config (r10, 144 µs). Further thread-count / phase-overlap experiments
// were neutral-to-negative (r11); the floor is not wave-schedulable latency.
__global__ __launch_bounds__(TPB) void k10_solve(const float* __restrict__ G,
                                                 const float* __restrict__ C,
                                                 const float* __restrict__ W0,
                                                 float* __restrict__ Wnew) {
    __shared__ __align__(16) float M[129 * 140];
    __shared__ __align__(16) float LpT[PW * 132];   // [k][r], per-panel
    __shared__ float invD[129];
    int tid = threadIdx.x;
    int lane = tid & 63, wv = tid >> 6;
    for (int e = tid; e < 129 * 129; e += TPB) {
        int i = e / 129, j = e % 129;
        M[i * 140 + j] = G[e] + (i == j ? 1.f : 0.f);
    }
    for (int i = tid; i < 129; i += TPB) M[i * 140 + 129] = 0.f;
    for (int e = tid; e < 1290; e += TPB) {
        int i = e / 10, c = e % 10;
        M[i * 140 + 130 + c] = W0[e] + C[e];
    }
    __syncthreads();

    for (int k0 = 0; k0 < 128; k0 += PW) {
        const int kend = k0 + PW;
        // --- A: 16x16 diagonal factor in registers (wave 0, lanes 0..15) ---
        if (wv == 0) {
            bool act = lane < PW;
            int r  = k0 + lane;
            int rc = act ? r : k0;
            float u[PW], Lr[PW];
#pragma unroll
            for (int j = 0; j < PW; ++j) u[j] = M[rc * 140 + k0 + j];
            float dval = u[0];
#pragma unroll
            for (int k = 0; k < PW; ++k) {
                if (lane == k) dval = u[k];
                float piv = __shfl(u[k], k);
                float f   = u[k] / piv;
                float fm  = (act && lane > k) ? f : 0.f;
                Lr[k] = fm;
#pragma unroll
                for (int j = 0; j < PW; ++j)
                    if (j > k) u[j] -= fm * __shfl(u[j], k);
            }
            if (act) {
#pragma unroll
                for (int j = 0; j < PW; ++j)
                    if (j >= lane) M[r * 140 + k0 + j] = u[j];
#pragma unroll
                for (int k = 0; k < PW; ++k)
                    if (k < lane) LpT[k * 132 + r] = Lr[k];
                invD[r] = 1.f / dval;
            }
        }
        __syncthreads();
        // --- B: L21 TRSM row-parallel (rows kend..128) -> LpT rows >= kend ---
        {
            int r = kend + tid;
            if (r <= 128) {
                float a[PW], l[PW];
                float4 a4[4];
#pragma unroll
                for (int q = 0; q < 4; ++q) a4[q] = *(const float4*)&M[r * 140 + k0 + q * 4];
#pragma unroll
                for (int q = 0; q < 4; ++q) {
                    a[q * 4 + 0] = a4[q].x; a[q * 4 + 1] = a4[q].y;
                    a[q * 4 + 2] = a4[q].z; a[q * 4 + 3] = a4[q].w;
                }
#pragma unroll
                for (int k = 0; k < PW; ++k) {
                    float v = a[k];
#pragma unroll
                    for (int m = 0; m < PW; ++m)
                        if (m < k) v -= l[m] * M[(k0 + m) * 140 + k0 + k];
                    l[k] = v * invD[k0 + k];
                    LpT[k * 132 + r] = l[k];
                }
            }
        }
        // --- C: U12 := L11^{-1} U12 (cols kend..139 incl. RHS), column-parallel ---
        for (int j = kend + tid; j < 140; j += TPB) {
            float u[PW];
#pragma unroll
            for (int kk = 0; kk < PW; ++kk) {
                float v = M[(k0 + kk) * 140 + j];
#pragma unroll
                for (int m = 0; m < PW; ++m)
                    if (m < kk) v -= LpT[m * 132 + k0 + kk] * u[m];
                u[kk] = v;
                M[(k0 + kk) * 140 + j] = v;
            }
        }
        __syncthreads();
        // --- D: trailing rank-16 update, 4 rows x 4 cols per task, b128 everywhere ---
        const int R = 129 - kend, Jn = 140 - kend;
        const int nrt = (R + 3) >> 2, nct = (Jn + 3) >> 2;
        for (int t = tid; t < nrt * nct; t += TPB) {
            int tr = t % nrt, tc = t / nrt;
            int r0 = kend + tr * 4;
            int j0 = kend + tc * 4;
            float4 s0 = {0, 0, 0, 0}, s1 = {0, 0, 0, 0}, s2 = {0, 0, 0, 0}, s3 = {0, 0, 0, 0};
#pragma unroll
            for (int kk = 0; kk < PW; ++kk) {
                float4 L4 = *(const float4*)&LpT[kk * 132 + r0];
                float4 U4 = *(const float4*)&M[(k0 + kk) * 140 + j0];
                s0.x += L4.x * U4.x; s0.y += L4.x * U4.y; s0.z += L4.x * U4.z; s0.w += L4.x * U4.w;
                s1.x += L4.y * U4.x; s1.y += L4.y * U4.y; s1.z += L4.y * U4.z; s1.w += L4.y * U4.w;
                s2.x += L4.z * U4.x; s2.y += L4.z * U4.y; s2.z += L4.z * U4.z; s2.w += L4.z * U4.w;
                s3.x += L4.w * U4.x; s3.y += L4.w * U4.y; s3.z += L4.w * U4.z; s3.w += L4.w * U4.w;
            }
            float4 sv[4] = {s0, s1, s2, s3};
#pragma unroll
            for (int i = 0; i < 4; ++i) {
                int r = r0 + i;
                if (r <= 128) {
                    float4 mv = *(const float4*)&M[r * 140 + j0];
                    mv.x -= sv[i].x; mv.y -= sv[i].y; mv.z -= sv[i].z; mv.w -= sv[i].w;
                    *(float4*)&M[r * 140 + j0] = mv;
                }
            }
        }
        __syncthreads();
    }
    if (tid == 0) invD[128] = 1.f / M[128 * 140 + 128];
    __syncthreads();
    // --- back substitution: RHS register-resident on wave 0, shfl broadcast ---
    if (wv == 0) {
        int r0 = lane, r1 = lane + 64;
        float b0[10], b1[10], b2[10];
#pragma unroll
        for (int c = 0; c < 10; ++c) {
            b0[c] = M[r0 * 140 + 130 + c];
            b1[c] = M[r1 * 140 + 130 + c];
            b2[c] = (lane == 0) ? M[128 * 140 + 130 + c] : 0.f;
        }
        float id0 = invD[r0], id1 = invD[r1];
        float id2 = (lane == 0) ? invD[128] : 0.f;
        for (int k = 128; k >= 0; --k) {
            int src = k & 63, slot = k >> 6;
            if (lane == src) {
                if (slot == 2) {
#pragma unroll
                    for (int c = 0; c < 10; ++c) b2[c] *= id2;
                } else if (slot == 1) {
#pragma unroll
                    for (int c = 0; c < 10; ++c) b1[c] *= id1;
                } else {
#pragma unroll
                    for (int c = 0; c < 10; ++c) b0[c] *= id0;
                }
            }
            float m0 = (r0 < k) ? M[r0 * 140 + k] : 0.f;
            float m1 = (r1 < k) ? M[r1 * 140 + k] : 0.f;
#pragma unroll
            for (int c = 0; c < 10; ++c) {
                float v = (slot == 2) ? b2[c] : (slot == 1 ? b1[c] : b0[c]);
                float xc = __shfl(v, src);
                b0[c] -= m0 * xc;
                b1[c] -= m1 * xc;
            }
        }
#pragma unroll
        for (int c = 0; c < 10; ++c) {
            Wnew[r0 * 10 + c] = b0[c];
            Wnew[r1 * 10 + c] = b1[c];
            if (lane == 0) Wnew[1280 + c] = b2[c];
        }
    }
}

// k11: out = Phi @ Wnew  ([4096][10])
__global__ __launch_bounds__(TPB) void k11_out(const float* __restrict__ Phi,
                                               const float* __restrict__ Wnew,
                                               float* __restrict__ out) {
    __shared__ float Wl[1290];
    int tid = threadIdx.x;
    for (int i = tid; i < 1290; i += TPB) Wl[i] = Wnew[i];
    __syncthreads();
    int idx = blockIdx.x * TPB + tid;
    int n = idx / 10, j = idx % 10;
    float s = 0.f;
    for (int d = 0; d < 129; ++d) s += Phi[n * 129 + d] * Wl[d * 10 + j];
    out[idx] = s;
}

extern "C" void kernel_launch(void* const* d_in, const int* in_sizes, int n_in,
                              void* d_out, int out_size, void* d_ws, size_t ws_size,
                              hipStream_t stream) {
    const float* x   = (const float*)d_in[0];
    const float* y   = (const float*)d_in[1];
    const float* w1  = (const float*)d_in[2];
    const float* g1  = (const float*)d_in[4];
    const float* be1 = (const float*)d_in[5];
    const float* w2  = (const float*)d_in[6];
    const float* b2  = (const float*)d_in[7];
    const float* g2  = (const float*)d_in[8];
    const float* be2 = (const float*)d_in[9];
    const float* fw  = (const float*)d_in[10];
    const float* fb  = (const float*)d_in[11];
    const float* W0  = (const float*)d_in[12];
    float* out = (float*)d_out;
    float* ws  = (float*)d_ws;
    if (ws_size < WS_TOTAL * 4ull) return;

    unsigned* wAg_u = (unsigned*)(ws + WS_WAG);
    unsigned* fwp_u = (unsigned*)(ws + WS_FWP);
    const unsigned short* wAg_h = (const unsigned short*)wAg_u;
    const unsigned short* fwp_h = (const unsigned short*)fwp_u;
    float* sc1     = ws + WS_SC1;
    float* sh1     = ws + WS_SH1;
    float* sck     = ws + WS_SCK;
    float* shk     = ws + WS_SHK;
    float* G       = ws + WS_G;
    float* C       = ws + WS_C;
    float* Wnew    = ws + WS_WNEW;
    float* qpart   = ws + WS_BN1PART;
    float* bn2part = ws + WS_BN2PART;
    float* Phi     = ws + WS_PHI;
    float* fpart   = ws + WS_FPART;
    float* Gpart   = ws + WS_GPART;
    float* Cpart   = ws + WS_CPART;
    float* pmax    = ws + WS_PMAX;
    unsigned short* pminh = (unsigned short*)(ws + WS_PMINH);

    kW_pack<<<820, TPB, 0, stream>>>(w2, fw, wAg_u, fwp_u);
    k1_conv1_stats<<<256, TPB, 0, stream>>>(x, qpart);
    k2_bn1_final<<<1, 64, 0, stream>>>(qpart, w1, g1, be1, sc1, sh1);
    k34_conv2_mfma<<<4096, TPB, 0, stream>>>(x, w1, sc1, sh1, wAg_h, b2, pmax, pminh, bn2part);
    k5_bn2_final<<<64, TPB, 0, stream>>>(bn2part, g2, be2, sck, shk);
    k7_fc1_mfma<<<448, TPB, 0, stream>>>(pmax, pminh, sck, shk, fwp_h, fpart);
    k7b_relu<<<2048, TPB, 0, stream>>>(fpart, fb, Phi);
    k8_gram<<<128, TPB, 0, stream>>>(Phi, y, Gpart, Cpart);
    k9_reduce<<<71, TPB, 0, stream>>>(Gpart, Cpart, G, C);
    k10_solve<<<1, TPB, 0, stream>>>(G, C, W0, Wnew);
    k11_out<<<160, TPB, 0, stream>>>(Phi, Wnew, out);
}